// Round 3
// baseline (1944.966 us; speedup 1.0000x reference)
//
#include <hip/hip_runtime.h>

#define DDIM 80
#define PLANE 6400
#define VOL 512000
#define HALFV 4
#define NVOL 8
#define NTOT (NVOL*VOL)

#define TY 8
#define CZ 10
#define NYT 10          // 80/TY
#define NZC 8           // 80/CZ
#define NCH 20          // float4 chunks per 80-float row
#define RP 84           // padded row length (floats) for E-rings
#define BLK 320
#define KIT 3           // fused iterations per kernel
#define R1R 14          // TY + 2*(KIT-1) + 2
#define R2R 12
#define R3R 10
#define SRR 16          // src ring rows = R1R + 2

__device__ __forceinline__ float4 f4min(float4 a, float4 b) {
    return make_float4(fminf(a.x,b.x), fminf(a.y,b.y), fminf(a.z,b.z), fminf(a.w,b.w));
}
__device__ __forceinline__ float4 f4max(float4 a, float4 b) {
    return make_float4(fmaxf(a.x,b.x), fmaxf(a.y,b.y), fmaxf(a.z,b.z), fmaxf(a.w,b.w));
}
__device__ __forceinline__ int slot3(int v){ return (v + 9) % 3; }   // v >= -9
__device__ __forceinline__ int slot4(int v){ return (v + 8) % 4; }   // v >= -8
__device__ __forceinline__ float updf(float s, float d){ return s + fmaxf(d - s*d, 0.0f); }

// One kernel = 3 skeletonization iterations, 5-stage rolling-z LDS pipeline:
// SR(src) -> E1 -> E2 -> E3 rings; upd1/2/3 at matching depths; SK ring stages skel.
template<bool FIRST, bool LASTK>
__global__ __launch_bounds__(BLK) void fused3_k(const float* __restrict__ xin,
                                                const float* __restrict__ yin,
                                                const float* __restrict__ a,
                                                float* __restrict__ eout,
                                                float* __restrict__ skel)
{
    __shared__ float SR[4][SRR][DDIM];   // raw src ring (unpadded, 20480 B)
    __shared__ float E1[3][R1R][RP];     // 14112 B
    __shared__ float E2[3][R2R][RP];     // 12096 B
    __shared__ float E3[3][R3R][RP];     // 10080 B
    __shared__ float SK[3][TY][DDIM];    // 7680 B  (total 64448 <= 64K)

    const int b = blockIdx.x;
    const int v = b / (NYT*NZC);
    const int rem = b - v*(NYT*NZC);
    const int yt = rem / NZC;
    const int zci = rem - yt*NZC;
    const int y0 = yt*TY;
    const int z0 = zci*CZ;

    const float* __restrict__ src =
        FIRST ? ((v < HALFV) ? (xin + v*VOL) : (yin + (v-HALFV)*VOL)) : (a + v*VOL);
    float* __restrict__ ev;
    if constexpr (!LASTK) ev = eout + v*VOL; else ev = nullptr;
    float* __restrict__ skv = skel + v*VOL;

    const int tid = threadIdx.x;
    const int r20 = tid / NCH;
    const int c   = tid - r20*NCH;
    const int x4  = 4*c;

    // ---- src global address for ring row (all 320 threads: 16 rows x 20 chunks) ----
    auto srAddr = [&](int zs) -> const float* {
        const int gy  = y0 - 4 + r20;
        const int gyc = min(max(gy, 0), DDIM-1);
        const int zcl = min(max(zs, 0), DDIM-1);
        return src + zcl*PLANE + gyc*DDIM + x4;
    };
    auto srStore = [&](int zs, float4 pf) {
        *(float4*)&SR[slot4(zs)][r20][x4] = pf;
    };

    // ---- stage1: erode(SR) -> E1, slice zs (virtual) ----
    auto stage1 = [&](int zs) {
        if (tid < R1R*NCH) {
            const int r  = r20;
            const int gy = y0 - 3 + r;
            const int gyc = min(max(gy, 0), DDIM-1);
            const int i0 = gyc - y0 + 4;             // center row in SR
            const int sc0 = slot4(zs), scA = slot4(zs-1), scB = slot4(zs+1);
            const float* rc = &SR[sc0][i0][0];
            const float4 c4 = *(const float4*)(rc + x4);
            const float lf = (c>0)  ? rc[x4-1] : c4.x;
            const float rt = (c<19) ? rc[x4+4] : c4.w;
            float4 m;
            m.x = fminf(fminf(lf, c4.x), c4.y);
            m.y = fminf(fminf(c4.x, c4.y), c4.z);
            m.z = fminf(fminf(c4.y, c4.z), c4.w);
            m.w = fminf(fminf(c4.z, c4.w), rt);
            m = f4min(m, *(const float4*)&SR[sc0][i0-1][x4]);
            m = f4min(m, *(const float4*)&SR[sc0][i0+1][x4]);
            m = f4min(m, *(const float4*)&SR[scA][i0][x4]);
            m = f4min(m, *(const float4*)&SR[scB][i0][x4]);
            *(float4*)&E1[slot3(zs)][r][x4] = m;
        }
    };

    // ---- stage j=2,3: erode(E_{j-1}) -> E_j, slice zs; stage3 writes through to global ----
    auto stageR = [&](int j, int zs) {
        const int rowsD = (j==2) ? R2R : R3R;
        if (tid < rowsD*NCH) {
            const int r  = r20;
            const int gy = y0 - (KIT-j) - 1 + r;
            const int gyc = min(max(gy, 0), DDIM-1);
            const int rb = r + (gyc - gy);           // source rows rb..rb+2
            const float* ring = (j==2) ? &E1[0][0][0] : &E2[0][0][0];
            const int rowsS = (j==2) ? R1R : R2R;
            const float* s0 = ring + slot3(zs)  *rowsS*RP;
            const float* sA = ring + slot3(zs-1)*rowsS*RP;
            const float* sB = ring + slot3(zs+1)*rowsS*RP;
            const float* rc = s0 + (rb+1)*RP;
            const float4 c4 = *(const float4*)(rc + x4);
            const float lf = (c>0)  ? rc[x4-1] : c4.x;
            const float rt = (c<19) ? rc[x4+4] : c4.w;
            float4 m;
            m.x = fminf(fminf(lf, c4.x), c4.y);
            m.y = fminf(fminf(c4.x, c4.y), c4.z);
            m.z = fminf(fminf(c4.y, c4.z), c4.w);
            m.w = fminf(fminf(c4.z, c4.w), rt);
            m = f4min(m, *(const float4*)(s0 + rb*RP + x4));
            m = f4min(m, *(const float4*)(s0 + (rb+2)*RP + x4));
            m = f4min(m, *(const float4*)(sA + (rb+1)*RP + x4));
            m = f4min(m, *(const float4*)(sB + (rb+1)*RP + x4));
            float* dst = ((j==2) ? &E2[0][0][0] : &E3[0][0][0]) + slot3(zs)*rowsD*RP;
            *(float4*)(dst + r*RP + x4) = m;
            if (j==3 && !LASTK) {
                if (zs >= z0 && zs < z0+CZ && r >= 1 && r <= TY)
                    *(float4*)(ev + zs*PLANE + (y0 + r - 1)*DDIM + x4) = m;
            }
        }
    };

    // ---- upd j: dilate(E_j)[zu] + skeleton update at slice zu ----
    auto updX = [&](int j, int zu) {
        if (tid < TY*NCH) {
            const int ty = r20;                      // 0..7
            const int gy = y0 + ty;
            const float* ring = (j==1) ? &E1[0][0][0] : (j==2) ? &E2[0][0][0] : &E3[0][0][0];
            const int rows = (j==1) ? R1R : (j==2) ? R2R : R3R;
            const int r0 = ty + (KIT - j);
            const int sa = slot3(max(zu-1, 0)), sb = slot3(zu), sc = slot3(min(zu+1, DDIM-1));
            const int ss[3] = {sa, sb, sc};
            float4 vmax = make_float4(-1e30f, -1e30f, -1e30f, -1e30f);
            float lmax = -1e30f, rmax = -1e30f;
#pragma unroll
            for (int s = 0; s < 3; ++s) {
                const float* slice = ring + ss[s]*rows*RP;
#pragma unroll
                for (int l = 0; l < 3; ++l) {
                    const float* row = slice + (r0+l)*RP;
                    const float4 t = *(const float4*)(row + x4);
                    vmax = f4max(vmax, t);
                    lmax = fmaxf(lmax, (c>0)  ? row[x4-1] : t.x);
                    rmax = fmaxf(rmax, (c<19) ? row[x4+4] : t.w);
                }
            }
            float4 dm;
            dm.x = fmaxf(lmax, fmaxf(vmax.x, vmax.y));
            dm.y = fmaxf(vmax.x, fmaxf(vmax.y, vmax.z));
            dm.z = fmaxf(vmax.y, fmaxf(vmax.z, vmax.w));
            dm.w = fmaxf(fmaxf(vmax.z, vmax.w), rmax);
            float4 img;
            if (j==1)      img = *(const float4*)&SR[slot4(zu)][ty+4][x4];
            else if (j==2) img = *(const float4*)&E1[slot3(zu)][ty+3][x4];
            else           img = *(const float4*)&E2[slot3(zu)][ty+2][x4];
            float4 d;
            d.x = fmaxf(img.x - dm.x, 0.0f);
            d.y = fmaxf(img.y - dm.y, 0.0f);
            d.z = fmaxf(img.z - dm.z, 0.0f);
            d.w = fmaxf(img.w - dm.w, 0.0f);
            float4 s;
            if (j==1) {
                if (FIRST) { s = d; }
                else {
                    s = *(const float4*)(skv + zu*PLANE + gy*DDIM + x4);
                    s.x = updf(s.x, d.x); s.y = updf(s.y, d.y);
                    s.z = updf(s.z, d.z); s.w = updf(s.w, d.w);
                }
            } else {
                s = *(const float4*)&SK[slot3(zu)][ty][x4];
                s.x = updf(s.x, d.x); s.y = updf(s.y, d.y);
                s.z = updf(s.z, d.z); s.w = updf(s.w, d.w);
            }
            if (j < KIT) *(float4*)&SK[slot3(zu)][ty][x4] = s;
            else         *(float4*)(skv + zu*PLANE + gy*DDIM + x4) = s;
        }
    };

    // ---- preload src ring: slices z0-4, z0-3, z0-2 ----
    {
        float4 p0 = *(const float4*)srAddr(z0-4);
        float4 p1 = *(const float4*)srAddr(z0-3);
        float4 p2 = *(const float4*)srAddr(z0-2);
        srStore(z0-4, p0); srStore(z0-3, p1); srStore(z0-2, p2);
    }
    __syncthreads();

    // ---- pipelined main loop: steps S = -6 .. CZ-1 ----
    for (int S = -2*KIT; S < CZ; ++S) {
        const int z = z0 + S;
        // group 1: prefetch src slice z+5 (issue), erode slice z+3 (compute), store prefetch
        float4 pf;
        const bool doPf = (S <= CZ-2);
        if (doPf) pf = *(const float4*)srAddr(z+5);
        stage1(z + 3);
        if (doPf) srStore(z+5, pf);
        __syncthreads();
        // group 2
        if (S >= -4) stageR(2, z + 2);
        if (S >= -2 && S <= CZ-3) updX(1, z + 2);
        __syncthreads();
        // group 3
        if (S >= -2) stageR(3, z + 1);
        if (S >= -1 && S <= CZ-2) updX(2, z + 1);
        __syncthreads();
        // group 4
        if (S >= 0) updX(3, z);
    }
}

// 1024 blocks: 256 per volume, 2000 contiguous elems each. No atomics.
__global__ __launch_bounds__(256) void reduce_k(const float* __restrict__ x,
                                                const float* __restrict__ y,
                                                const float* __restrict__ skel,
                                                float* __restrict__ partials) {
    const int blk = blockIdx.x;
    const int v = blk >> 8;
    const int sub = blk & 255;
    const int base4 = (v * VOL + sub * 2000) >> 2;

    const float4* x4 = (const float4*)x;
    const float4* y4 = (const float4*)y;
    const float4* clp4 = (const float4*)(skel);
    const float4* cll4 = (const float4*)(skel + HALFV * VOL);

    float s1 = 0, s2 = 0, s3 = 0, s4 = 0;
    for (int j = threadIdx.x; j < 500; j += 256) {
        const int i4 = base4 + j;
        const float4 xv = x4[i4];
        const float4 yv = y4[i4];
        const float4 cp = clp4[i4];
        const float4 cl = cll4[i4];
        s1 += xv.x*cl.x + xv.y*cl.y + xv.z*cl.z + xv.w*cl.w;
        s2 += cl.x + cl.y + cl.z + cl.w;
        s3 += cp.x*yv.x + cp.y*yv.y + cp.z*yv.z + cp.w*yv.w;
        s4 += cp.x + cp.y + cp.z + cp.w;
    }
    for (int off = 32; off > 0; off >>= 1) {
        s1 += __shfl_down(s1, off);
        s2 += __shfl_down(s2, off);
        s3 += __shfl_down(s3, off);
        s4 += __shfl_down(s4, off);
    }
    __shared__ float sm[4][4];
    const int wave = threadIdx.x >> 6;
    if ((threadIdx.x & 63) == 0) {
        sm[wave][0] = s1; sm[wave][1] = s2; sm[wave][2] = s3; sm[wave][3] = s4;
    }
    __syncthreads();
    if (threadIdx.x == 0) {
        float a0 = 0, a1 = 0, a2 = 0, a3 = 0;
        for (int w = 0; w < 4; ++w) { a0 += sm[w][0]; a1 += sm[w][1]; a2 += sm[w][2]; a3 += sm[w][3]; }
        partials[blk*4 + 0] = a0;
        partials[blk*4 + 1] = a1;
        partials[blk*4 + 2] = a2;
        partials[blk*4 + 3] = a3;
    }
}

__global__ void final_k(const float* __restrict__ p, float* __restrict__ out) {
    __shared__ float sums[16];
    const int t = threadIdx.x;
    if (t < 16) {
        const int v = t >> 2, k = t & 3;
        float acc = 0.0f;
        for (int b = 0; b < 256; ++b) acc += p[((v << 8) + b)*4 + k];
        sums[t] = acc;
    }
    __syncthreads();
    if (t == 0) {
        float acc = 0.0f;
        for (int v = 0; v < 4; ++v) {
            const float tp      = sums[v*4 + 0];
            const float sum_cll = sums[v*4 + 1];
            const float tpc     = sums[v*4 + 2];
            const float sum_clp = sums[v*4 + 3];
            const float fn  = sum_cll - tp;
            const float fpc = sum_clp - tpc;
            const float clp2voll = (tpc + 1.0f) / (tpc + fpc + 1.0f);
            const float cll2volp = (tp + 1.0f) / (tp + fn + 1.0f);
            const float dc = 2.0f * clp2voll * cll2volp / (cll2volp + clp2voll + 1e-8f);
            acc += dc;
        }
        out[0] = 1.0f - acc * 0.25f;
    }
}

extern "C" void kernel_launch(void* const* d_in, const int* in_sizes, int n_in,
                              void* d_out, int out_size, void* d_ws, size_t ws_size,
                              hipStream_t stream) {
    const float* x = (const float*)d_in[0];
    const float* y = (const float*)d_in[1];
    float* out = (float*)d_out;

    float* bufA = (float*)d_ws;
    float* bufB = bufA + NTOT;
    float* skel = bufB + NTOT;
    float* partials = skel + NTOT;   // 4096 floats

    const int GRID = NVOL * NYT * NZC;   // 640

    // kernel 0: iterations 0,1,2  (src = inputs, skel init inside)
    fused3_k<true, false><<<GRID, BLK, 0, stream>>>(x, y, nullptr, bufA, skel);
    // kernels 1..15: iterations 3t..3t+2
    for (int t = 1; t <= 15; ++t) {
        fused3_k<false, false><<<GRID, BLK, 0, stream>>>(nullptr, nullptr, bufA, bufB, skel);
        float* tmp = bufA; bufA = bufB; bufB = tmp;
    }
    // kernel 16: iterations 48,49,50 (no erode-out write)
    fused3_k<false, true><<<GRID, BLK, 0, stream>>>(nullptr, nullptr, bufA, nullptr, skel);

    reduce_k<<<1024, 256, 0, stream>>>(x, y, skel, partials);
    final_k<<<1, 64, 0, stream>>>(partials, out);
}

// Round 4
// 992.562 us; speedup vs baseline: 1.9595x; 1.9595x over previous
//
#include <hip/hip_runtime.h>

#define DDIM 80
#define PLANE 6400
#define VOL 512000
#define HALFV 4
#define NVOL 8
#define NTOT (NVOL*VOL)

#define TY 10
#define CZ 8
#define NYT 8           // 80/TY
#define NZC 10          // 80/CZ
#define NCH 20          // float4 chunks per 80-float row
#define RP 84           // padded row floats in E ring
#define ER (TY + 2)     // 12 eroded rows per slice
#define BLK 256

__device__ __forceinline__ float4 f4min(float4 a, float4 b) {
    return make_float4(fminf(a.x,b.x), fminf(a.y,b.y), fminf(a.z,b.z), fminf(a.w,b.w));
}
__device__ __forceinline__ float4 f4max(float4 a, float4 b) {
    return make_float4(fmaxf(a.x,b.x), fmaxf(a.y,b.y), fmaxf(a.z,b.z), fmaxf(a.w,b.w));
}
__device__ __forceinline__ int slot4(int v){ return (v + 8) & 3; }   // v >= -8
__device__ __forceinline__ float updf(float s, float d){ return s + fmaxf(d - s*d, 0.0f); }

struct EIn { float4 c, zA, zB, yA, yB; float lf, rt; };
struct DIn { float4 img, sk; };

// One skeletonization iteration. 4-slot E ring, ONE barrier per z-step,
// all global loads prefetched one step ahead (full unroll keeps them in SSA regs).
template<bool FIRST, bool LASTK>
__global__ __launch_bounds__(BLK) void iter_k(const float* __restrict__ xin,
                                              const float* __restrict__ yin,
                                              const float* __restrict__ a,
                                              float* __restrict__ eout,
                                              float* __restrict__ skel)
{
    __shared__ float E[4][ER][RP];   // 16128 B

    const int b = blockIdx.x;
    const int v = b / (NYT*NZC);
    const int rem = b - v*(NYT*NZC);
    const int yt = rem / NZC;
    const int zci = rem - yt*NZC;
    const int y0 = yt*TY;
    const int z0 = zci*CZ;

    const float* __restrict__ src =
        FIRST ? ((v < HALFV) ? (xin + v*VOL) : (yin + (v-HALFV)*VOL)) : (a + v*VOL);
    float* __restrict__ ev = LASTK ? nullptr : (eout + v*VOL);
    float* __restrict__ skv = skel + v*VOL;

    const int tid = threadIdx.x;
    const int r = tid / NCH;          // erode row 0..12 (valid <12), dilate row 0..9 (valid <10)
    const int c = tid - r*NCH;        // chunk 0..19
    const int x4 = 4*c;

    // issue the 7 global loads for erode of (virtual) slice zs
    auto loadE = [&](int zs, EIn& e) {
        if (tid < ER*NCH) {
            const int gy  = y0 - 1 + r;
            const int gyc = min(max(gy, 0), DDIM-1);
            const int zcl = min(max(zs, 0), DDIM-1);
            const int zm = max(zcl-1, 0), zp = min(zcl+1, DDIM-1);
            const int ym = max(gyc-1, 0), yp = min(gyc+1, DDIM-1);
            const float* rc = src + zcl*PLANE + gyc*DDIM;
            e.c  = *(const float4*)(rc + x4);
            e.lf = rc[max(x4-1, 0)];          // c==0 -> rc[0]==c.x (exact clamp semantics)
            e.rt = rc[min(x4+4, DDIM-1)];     // c==19 -> rc[79]==c.w
            e.zA = *(const float4*)(src + zm*PLANE + gyc*DDIM + x4);
            e.zB = *(const float4*)(src + zp*PLANE + gyc*DDIM + x4);
            e.yA = *(const float4*)(src + zcl*PLANE + ym*DDIM + x4);
            e.yB = *(const float4*)(src + zcl*PLANE + yp*DDIM + x4);
        }
    };

    // finish erode of slice zs from prefetched regs, store to E ring (+ global e)
    auto erodeStore = [&](int zs, const EIn& e) {
        if (tid < ER*NCH) {
            float4 m;
            m.x = fminf(fminf(e.lf,  e.c.x), e.c.y);
            m.y = fminf(fminf(e.c.x, e.c.y), e.c.z);
            m.z = fminf(fminf(e.c.y, e.c.z), e.c.w);
            m.w = fminf(fminf(e.c.z, e.c.w), e.rt);
            m = f4min(m, f4min(f4min(e.zA, e.zB), f4min(e.yA, e.yB)));
            *(float4*)&E[slot4(zs)][r][x4] = m;
            if constexpr (!LASTK) {
                if (r >= 1 && r <= TY && zs >= z0 && zs < z0 + CZ)
                    *(float4*)(ev + zs*PLANE + (y0 + r - 1)*DDIM + x4) = m;
            }
        }
    };

    // issue img (+skel) loads for dilate/update at slice z
    auto loadD = [&](int z, DIn& d) {
        if (tid < TY*NCH) {
            const int off = z*PLANE + (y0 + r)*DDIM + x4;
            d.img = *(const float4*)(src + off);
            if constexpr (!FIRST) d.sk = *(const float4*)(skv + off);
        }
    };

    // dilate(E)[z] + skeleton update
    auto dilateUpd = [&](int z, const DIn& d) {
        if (tid < TY*NCH) {
            const int ty = r;
            const int gy = y0 + ty;
            const int sa = slot4(z-1), sb = slot4(z), sc = slot4(z+1);
            const int ss[3] = {sa, sb, sc};
            float4 vmax = make_float4(-1e30f, -1e30f, -1e30f, -1e30f);
            float lmax = -1e30f, rmax = -1e30f;
#pragma unroll
            for (int s = 0; s < 3; ++s) {
#pragma unroll
                for (int l = 0; l < 3; ++l) {
                    const float* row = &E[ss[s]][ty + l][0];
                    const float4 t = *(const float4*)(row + x4);
                    vmax = f4max(vmax, t);
                    lmax = fmaxf(lmax, row[max(x4-1, 0)]);
                    rmax = fmaxf(rmax, row[min(x4+4, DDIM-1)]);
                }
            }
            float4 dm;
            dm.x = fmaxf(lmax, fmaxf(vmax.x, vmax.y));
            dm.y = fmaxf(vmax.x, fmaxf(vmax.y, vmax.z));
            dm.z = fmaxf(vmax.y, fmaxf(vmax.z, vmax.w));
            dm.w = fmaxf(fmaxf(vmax.z, vmax.w), rmax);

            float4 dl;
            dl.x = fmaxf(d.img.x - dm.x, 0.0f);
            dl.y = fmaxf(d.img.y - dm.y, 0.0f);
            dl.z = fmaxf(d.img.z - dm.z, 0.0f);
            dl.w = fmaxf(d.img.w - dm.w, 0.0f);
            float4 s;
            if constexpr (FIRST) {
                s = dl;
            } else {
                s = d.sk;
                s.x = updf(s.x, dl.x); s.y = updf(s.y, dl.y);
                s.z = updf(s.z, dl.z); s.w = updf(s.w, dl.w);
            }
            *(float4*)(skv + z*PLANE + gy*DDIM + x4) = s;
        }
    };

    // ---- prologue: erode z0-1, z0; prefetch step-0 inputs ----
    EIn eA, eB;
    DIn dA, dB;
    loadE(z0-1, eA);
    loadE(z0,   eB);
    erodeStore(z0-1, eA);
    erodeStore(z0,   eB);
    loadE(z0+1, eA);          // consumed at S=0
    loadD(z0,   dA);
    __syncthreads();

    // ---- main loop: one barrier per z-step ----
#pragma unroll
    for (int S = 0; S < CZ; ++S) {
        const int z = z0 + S;
        if (S + 1 < CZ) {              // prefetch next step's inputs
            loadE(z + 2, eB);
            loadD(z + 1, dB);
        }
        erodeStore(z + 1, eA);         // E slot (z+1)%4 — disjoint from prev dilate reads
        __syncthreads();
        dilateUpd(z, dA);
        if (S + 1 < CZ) { eA = eB; dA = dB; }
    }
}

// 1024 blocks: 256 per volume, 2000 contiguous elems each. No atomics.
__global__ __launch_bounds__(256) void reduce_k(const float* __restrict__ x,
                                                const float* __restrict__ y,
                                                const float* __restrict__ skel,
                                                float* __restrict__ partials) {
    const int blk = blockIdx.x;
    const int v = blk >> 8;
    const int sub = blk & 255;
    const int base4 = (v * VOL + sub * 2000) >> 2;

    const float4* x4 = (const float4*)x;
    const float4* y4 = (const float4*)y;
    const float4* clp4 = (const float4*)(skel);
    const float4* cll4 = (const float4*)(skel + HALFV * VOL);

    float s1 = 0, s2 = 0, s3 = 0, s4 = 0;
    for (int j = threadIdx.x; j < 500; j += 256) {
        const int i4 = base4 + j;
        const float4 xv = x4[i4];
        const float4 yv = y4[i4];
        const float4 cp = clp4[i4];
        const float4 cl = cll4[i4];
        s1 += xv.x*cl.x + xv.y*cl.y + xv.z*cl.z + xv.w*cl.w;
        s2 += cl.x + cl.y + cl.z + cl.w;
        s3 += cp.x*yv.x + cp.y*yv.y + cp.z*yv.z + cp.w*yv.w;
        s4 += cp.x + cp.y + cp.z + cp.w;
    }
    for (int off = 32; off > 0; off >>= 1) {
        s1 += __shfl_down(s1, off);
        s2 += __shfl_down(s2, off);
        s3 += __shfl_down(s3, off);
        s4 += __shfl_down(s4, off);
    }
    __shared__ float sm[4][4];
    const int wave = threadIdx.x >> 6;
    if ((threadIdx.x & 63) == 0) {
        sm[wave][0] = s1; sm[wave][1] = s2; sm[wave][2] = s3; sm[wave][3] = s4;
    }
    __syncthreads();
    if (threadIdx.x == 0) {
        float a0 = 0, a1 = 0, a2 = 0, a3 = 0;
        for (int w = 0; w < 4; ++w) { a0 += sm[w][0]; a1 += sm[w][1]; a2 += sm[w][2]; a3 += sm[w][3]; }
        partials[blk*4 + 0] = a0;
        partials[blk*4 + 1] = a1;
        partials[blk*4 + 2] = a2;
        partials[blk*4 + 3] = a3;
    }
}

__global__ void final_k(const float* __restrict__ p, float* __restrict__ out) {
    __shared__ float sums[16];
    const int t = threadIdx.x;
    if (t < 16) {
        const int v = t >> 2, k = t & 3;
        float acc = 0.0f;
        for (int b = 0; b < 256; ++b) acc += p[((v << 8) + b)*4 + k];
        sums[t] = acc;
    }
    __syncthreads();
    if (t == 0) {
        float acc = 0.0f;
        for (int v = 0; v < 4; ++v) {
            const float tp      = sums[v*4 + 0];
            const float sum_cll = sums[v*4 + 1];
            const float tpc     = sums[v*4 + 2];
            const float sum_clp = sums[v*4 + 3];
            const float fn  = sum_cll - tp;
            const float fpc = sum_clp - tpc;
            const float clp2voll = (tpc + 1.0f) / (tpc + fpc + 1.0f);
            const float cll2volp = (tp + 1.0f) / (tp + fn + 1.0f);
            const float dc = 2.0f * clp2voll * cll2volp / (cll2volp + clp2voll + 1e-8f);
            acc += dc;
        }
        out[0] = 1.0f - acc * 0.25f;
    }
}

extern "C" void kernel_launch(void* const* d_in, const int* in_sizes, int n_in,
                              void* d_out, int out_size, void* d_ws, size_t ws_size,
                              hipStream_t stream) {
    const float* x = (const float*)d_in[0];
    const float* y = (const float*)d_in[1];
    float* out = (float*)d_out;

    float* bufA = (float*)d_ws;
    float* bufB = bufA + NTOT;
    float* skel = bufB + NTOT;
    float* partials = skel + NTOT;   // 4096 floats

    const int GRID = NVOL * NYT * NZC;   // 640

    // iteration 0 (src = inputs, skel init)
    iter_k<true, false><<<GRID, BLK, 0, stream>>>(x, y, nullptr, bufA, skel);
    // iterations 1..49
    for (int t = 1; t <= 49; ++t) {
        iter_k<false, false><<<GRID, BLK, 0, stream>>>(nullptr, nullptr, bufA, bufB, skel);
        float* tmp = bufA; bufA = bufB; bufB = tmp;
    }
    // iteration 50: no e output needed
    iter_k<false, true><<<GRID, BLK, 0, stream>>>(nullptr, nullptr, bufA, nullptr, skel);

    reduce_k<<<1024, 256, 0, stream>>>(x, y, skel, partials);
    final_k<<<1, 64, 0, stream>>>(partials, out);
}